// Round 20
// baseline (38.885 us; speedup 1.0000x reference)
//
#include <hip/hip_runtime.h>
#include <hip/hip_bf16.h>
#include <math.h>

#define NSPK 2048
#define G 10
#define D 256
#define NG (NSPK * G)
#define LOG2E 1.4426950408889634f
#define LN2   0.6931471805599453f
#define FP8SCALE 16.0f        // both operands scaled x16 -> acc = 256*cos

typedef __attribute__((ext_vector_type(16))) float f32x16;
typedef __attribute__((ext_vector_type(8))) int v8i;
typedef __attribute__((ext_vector_type(4))) int i32x4;

__device__ __forceinline__ float dot4(float4 a, float4 b) {
    return a.x * b.x + a.y * b.y + a.z * b.z + a.w * b.w;
}
// pack 4 floats -> 4 fp8 e4m3 bytes (OCP, RNE/sat per HW cvt)
__device__ __forceinline__ int pk4_fp8(float a, float b, float c, float d) {
    int v = __builtin_amdgcn_cvt_pk_fp8_f32(a, b, 0, false);   // bytes 0,1
    v = __builtin_amdgcn_cvt_pk_fp8_f32(c, d, v, true);        // bytes 2,3
    return v;
}

// ---------------- Kernel A: per-speaker prep (wave-per-speaker) ----------------
// Writes (fp8 e4m3, values x16), K=64-MFMA fragment-friendly layout, SAME rule
// for both matrices (per 32-row tile of 8192 B):
//   byte(row, k) = tile*8192 + (k>>5)*1024 + ((k>>4)&1)*512 + (row&31)*16 + (k&15)
//   dlarg[r] = (w*clip(cos(x_r, exc_centroid)) + b - 5) * log2(e)   (fp32 exact)
// Block 0 also zeroes the 16B atomic accumulator used by the fused merge.
__global__ __launch_bounds__(256) void prep_kernel(
    const float* __restrict__ x, const float* __restrict__ wp, const float* __restrict__ bp,
    unsigned char* __restrict__ xb2, unsigned char* __restrict__ cb, float* __restrict__ dlarg,
    float* __restrict__ acc4)
{
    if (blockIdx.x == 0 && threadIdx.x < 4) acc4[threadIdx.x] = 0.0f;

    const int lane = threadIdx.x & 63;
    const int n = blockIdx.x * 4 + (threadIdx.x >> 6);
    const int d0 = lane * 4;
    const float* xr = x + (size_t)n * G * D + d0;

    float4 xg[G];
    float4 S4 = {0.f, 0.f, 0.f, 0.f};
    #pragma unroll
    for (int g = 0; g < G; ++g) {
        xg[g] = *(const float4*)(xr + g * D);
        S4.x += xg[g].x; S4.y += xg[g].y; S4.z += xg[g].z; S4.w += xg[g].w;
    }

    float arr[20];
    #pragma unroll
    for (int g = 0; g < G; ++g) {
        arr[g]      = dot4(xg[g], xg[g]);   // xx
        arr[10 + g] = dot4(xg[g], S4);      // xs
    }
    #pragma unroll
    for (int i = 0; i < 20; ++i) {
        float v = arr[i];
        #pragma unroll
        for (int off = 1; off < 64; off <<= 1) v += __shfl_xor(v, off);
        arr[i] = v;
    }
    float SS = 0.f;
    #pragma unroll
    for (int g = 0; g < G; ++g) SS += arr[10 + g];

    // fragment-layout byte offset for k = d0 within a 32-row tile
    const int koff = (d0 >> 5) * 1024 + ((d0 >> 4) & 1) * 512 + (d0 & 15);

    // centroid (norm folded, x16)
    const float cn = fmaxf(sqrtf(SS) * (1.0f / G), 1e-8f);
    const float cinv = FP8SCALE * (1.0f / G) / cn;
    {
        const int addr = (n >> 5) * 8192 + koff + (n & 31) * 16;
        *(int*)(cb + addr) = pk4_fp8(S4.x * cinv, S4.y * cinv, S4.z * cinv, S4.w * cinv);
    }

    // normalized x rows (x16)
    #pragma unroll
    for (int g = 0; g < G; ++g) {
        const int r = n * G + g;
        const float inv = FP8SCALE / fmaxf(sqrtf(arr[g]), 1e-8f);
        const int addr = (r >> 5) * 8192 + koff + (r & 31) * 16;
        *(int*)(xb2 + addr) = pk4_fp8(xg[g].x * inv, xg[g].y * inv, xg[g].z * inv, xg[g].w * inv);
    }

    if (lane < G) {
        const int g = lane;
        const float w = *wp, b = *bp;
        const float xx = arr[g], xs = arr[10 + g];
        const float x_norm = fmaxf(sqrtf(xx), 1e-8f);
        const float dotxe = (xs - xx) * (1.0f / (G - 1));
        const float ee = (SS - 2.f * xs + xx) * (1.0f / ((G - 1) * (G - 1)));
        const float e_norm = fmaxf(sqrtf(ee), 1e-8f);
        float cosd = fmaxf(dotxe / (x_norm * e_norm), 1e-6f);
        dlarg[n * G + g] = (fmaf(w, cosd, b) - 5.0f) * LOG2E;
    }
}

// ---------------- Kernel B: MX-fp8 K=64 MFMA GEMM + fixed-max LSE -------------
// r18's EXACT gemm (best measured: 36.8 total): 4 waves x 32 rows x 256 cols,
// 8 tiles, dbuf 2x8KB, plain syncthreads, single f32x16 acc, ROLLED t-loop,
// mfma_scale_f32_32x32x64_f8f6f4 with scales=1.0. r19's pair-buffer variant
// regressed (sched_barrier over-serialized; longer drain span) - reverted.
__global__ __launch_bounds__(256, 4) void gemm_softmax_kernel(
    const unsigned char* __restrict__ xb2, const unsigned char* __restrict__ cb,
    const float* __restrict__ dlarg,
    const float* __restrict__ wp, const float* __restrict__ bp,
    float* __restrict__ pm, float* __restrict__ ps)
{
    __shared__ __align__(16) char stage[2][8192];   // 2 x 8 KB

    const int tid = threadIdx.x;
    const int wv = tid >> 6, lane = tid & 63;
    const int l31 = lane & 31, l5 = lane >> 5;

    // XCD-aware decode: rt ≡ bid (mod 8)
    const int bid = blockIdx.x;
    const int xcd = bid & 7;
    const int idx = bid >> 3;             // 0..159
    const int rt = xcd + 8 * (idx % 20);  // 0..159
    const int cs = idx / 20;              // 0..7

    const int r0 = rt * 128, c0 = cs * 256;
    const int myrow = r0 + wv * 32 + l31;
    const float w2 = (*wp) * (LOG2E / 256.0f);      // acc = 256*cos
    const float b2 = ((*bp) - 5.0f) * LOG2E;
    const float dlpre = (dlarg[myrow] - b2) / w2;   // acc value that yields dlarg
    const int labadj = myrow / G - c0 - 4 * l5;

    // resident x fragments: 4 x v8i (two coalesced 16B loads each)
    v8i xf[4];
    const unsigned char* xrow = xb2 + (size_t)(rt * 4 + wv) * 8192 + l5 * 1024 + l31 * 16;
    #pragma unroll
    for (int m = 0; m < 4; ++m) {
        const i32x4 lo = *(const i32x4*)(xrow + m * 2048);
        const i32x4 hi = *(const i32x4*)(xrow + m * 2048 + 512);
        xf[m] = __builtin_shufflevector(lo, hi, 0, 1, 2, 3, 4, 5, 6, 7);
    }

    // staging: LINEAR 8KB tile copy (fragment layout pre-baked by prep)
    #define STAGE(bufi, tt) do {                                               \
        const unsigned char* base_ = cb + (size_t)c0 * 256 + (size_t)(tt) * 8192; \
        _Pragma("unroll")                                                      \
        for (int c_ = 0; c_ < 2; ++c_) {                                       \
            const int S_ = c_ * 256 + tid;                                     \
            __builtin_amdgcn_global_load_lds(                                  \
                (const __attribute__((address_space(1))) void*)(base_ + S_ * 16), \
                (__attribute__((address_space(3))) void*)                      \
                    ((char*)&stage[bufi][0] + S_ * 16),                        \
                16, 0, 0);                                                     \
        }                                                                      \
    } while (0)

    STAGE(0, 0);

    float s0 = 0.f, s1 = 0.f, m0 = -INFINITY;
    const char* lrow0 = &stage[0][0] + l5 * 1024 + l31 * 16;
    const char* lrow1 = &stage[1][0] + l5 * 1024 + l31 * 16;

    __syncthreads();

    #pragma unroll 1     // MUST stay rolled: full unroll spills (r14, WRITE 352 MB)
    for (int t = 0; t < 8; ++t) {
        const int bsel = t & 1;
        if (t < 7) STAGE(bsel ^ 1, t + 1);

        const char* lrow = bsel ? lrow1 : lrow0;
        f32x16 acc = {0,0,0,0,0,0,0,0,0,0,0,0,0,0,0,0};
        #pragma unroll
        for (int m = 0; m < 4; ++m) {
            const i32x4 lo = *(const i32x4*)(lrow + m * 2048);
            const i32x4 hi = *(const i32x4*)(lrow + m * 2048 + 512);
            const v8i cf = __builtin_shufflevector(lo, hi, 0, 1, 2, 3, 4, 5, 6, 7);
            acc = __builtin_amdgcn_mfma_scale_f32_32x32x64_f8f6f4(
                      cf, xf[m], acc, 0, 0, 0, 0x7F7F7F7F, 0, 0x7F7F7F7F);
        }

        // epilogue in place on acc
        const int target = labadj - t * 32;   // pat == target -> label col
        if ((unsigned)target < 32u && !(target & 4)) {
            #pragma unroll
            for (int reg = 0; reg < 16; ++reg) {
                const int pat = (reg & 3) + 8 * (reg >> 2);
                if (pat == target) acc[reg] = dlpre;   // fma below yields dlarg
            }
        }
        #pragma unroll
        for (int reg = 0; reg < 16; reg += 2) {
            const float l0 = fmaf(w2, fmaxf(acc[reg],     2.56e-4f), b2);
            const float l1 = fmaf(w2, fmaxf(acc[reg + 1], 2.56e-4f), b2);
            s0 += exp2f(l0);
            s1 += exp2f(l1);
            m0 = fmaxf(m0, fmaxf(l0, l1));   // fuses to v_max3_f32
        }
        __syncthreads();
    }
    #undef STAGE

    float s = s0 + s1;
    float m = m0;
    s += __shfl_xor(s, 32);
    m = fmaxf(m, __shfl_xor(m, 32));
    if (lane < 32) {
        pm[cs * NG + myrow] = m;
        ps[cs * NG + myrow] = s;
    }
}

// ---------------- Kernel C: merge + FUSED finalize (atomics, last block) ------
__global__ __launch_bounds__(256) void merge_kernel(
    const float* __restrict__ pm, const float* __restrict__ ps,
    const float* __restrict__ dlarg,
    float* __restrict__ acc4, float* __restrict__ out)
{
    const int r = blockIdx.x * 256 + threadIdx.x;
    float M = -INFINITY, S = 0.f;
    #pragma unroll
    for (int c = 0; c < 8; ++c) {
        M = fmaxf(M, pm[c * NG + r]);
        S += ps[c * NG + r];
    }
    const float dlv = dlarg[r];
    float loss = LN2 * (log2f(S) - dlv);
    float corr = (M == dlv) ? 1.0f : 0.0f;

    #pragma unroll
    for (int off = 1; off < 64; off <<= 1) {
        loss += __shfl_xor(loss, off);
        corr += __shfl_xor(corr, off);
    }
    __shared__ float rl[4], rc[4];
    const int wave = threadIdx.x >> 6, lane = threadIdx.x & 63;
    if (lane == 0) { rl[wave] = loss; rc[wave] = corr; }
    __syncthreads();
    if (threadIdx.x == 0) {
        const float Lb = rl[0] + rl[1] + rl[2] + rl[3];
        const float Cb = rc[0] + rc[1] + rc[2] + rc[3];
        atomicAdd(&acc4[0], Lb);
        atomicAdd(&acc4[1], Cb);
        __threadfence();
        const int old = atomicAdd((int*)(acc4 + 2), 1);
        if (old == (NG / 256) - 1) {            // last block: all adds visible
            const float L = atomicAdd(&acc4[0], 0.0f);
            const float C = atomicAdd(&acc4[1], 0.0f);
            out[0] = L / (float)NG;
            out[1] = 100.0f * C / (float)NG;
        }
    }
}

extern "C" void kernel_launch(void* const* d_in, const int* in_sizes, int n_in,
                              void* d_out, int out_size, void* d_ws, size_t ws_size,
                              hipStream_t stream) {
    const float* x  = (const float*)d_in[0];
    const float* wp = (const float*)d_in[1];
    const float* bp = (const float*)d_in[2];

    unsigned char* xb2 = (unsigned char*)d_ws;             // NG*D bytes   = 5.24 MB
    unsigned char* cb  = xb2 + (size_t)NG * D;             // NSPK*D bytes = 0.52 MB
    float* dlg  = (float*)(cb + (size_t)NSPK * D);         // NG floats
    float* pm   = dlg + NG;                                // 8*NG
    float* ps   = pm + 8 * NG;                             // 8*NG
    float* acc4 = ps + 8 * NG;                             // 4 floats (atomic acc)

    prep_kernel<<<NSPK / 4, 256, 0, stream>>>(x, wp, bp, xb2, cb, dlg, acc4);
    gemm_softmax_kernel<<<1280, 256, 0, stream>>>(xb2, cb, dlg, wp, bp, pm, ps);
    merge_kernel<<<NG / 256, 256, 0, stream>>>(pm, ps, dlg, acc4, (float*)d_out);
}

// Round 21
// 36.707 us; speedup vs baseline: 1.0593x; 1.0593x over previous
//
#include <hip/hip_runtime.h>
#include <hip/hip_bf16.h>
#include <math.h>

#define NSPK 2048
#define G 10
#define D 256
#define NG (NSPK * G)
#define LOG2E 1.4426950408889634f
#define LN2   0.6931471805599453f
#define FP8SCALE 16.0f        // both operands scaled x16 -> acc = 256*cos

typedef __attribute__((ext_vector_type(16))) float f32x16;
typedef __attribute__((ext_vector_type(8))) int v8i;
typedef __attribute__((ext_vector_type(4))) int i32x4;

__device__ __forceinline__ float dot4(float4 a, float4 b) {
    return a.x * b.x + a.y * b.y + a.z * b.z + a.w * b.w;
}
// pack 4 floats -> 4 fp8 e4m3 bytes (OCP, RNE/sat per HW cvt)
__device__ __forceinline__ int pk4_fp8(float a, float b, float c, float d) {
    int v = __builtin_amdgcn_cvt_pk_fp8_f32(a, b, 0, false);   // bytes 0,1
    v = __builtin_amdgcn_cvt_pk_fp8_f32(c, d, v, true);        // bytes 2,3
    return v;
}

// ---------------- Kernel A: per-speaker prep (wave-per-speaker) ----------------
// Writes (fp8 e4m3, values x16), K=64-MFMA fragment-friendly layout, SAME rule
// for both matrices (per 32-row tile of 8192 B):
//   byte(row, k) = tile*8192 + (k>>5)*1024 + ((k>>4)&1)*512 + (row&31)*16 + (k&15)
// -> a lane's 32-byte fragment = two 16B reads from two sequential 512B planes
//    (conflict-free LDS, coalesced global), staging stays a LINEAR 8KB copy.
//   dlarg[r] = (w*clip(cos(x_r, exc_centroid)) + b - 5) * log2(e)   (fp32 exact)
__global__ __launch_bounds__(256) void prep_kernel(
    const float* __restrict__ x, const float* __restrict__ wp, const float* __restrict__ bp,
    unsigned char* __restrict__ xb2, unsigned char* __restrict__ cb, float* __restrict__ dlarg)
{
    const int lane = threadIdx.x & 63;
    const int n = blockIdx.x * 4 + (threadIdx.x >> 6);
    const int d0 = lane * 4;
    const float* xr = x + (size_t)n * G * D + d0;

    float4 xg[G];
    float4 S4 = {0.f, 0.f, 0.f, 0.f};
    #pragma unroll
    for (int g = 0; g < G; ++g) {
        xg[g] = *(const float4*)(xr + g * D);
        S4.x += xg[g].x; S4.y += xg[g].y; S4.z += xg[g].z; S4.w += xg[g].w;
    }

    float arr[20];
    #pragma unroll
    for (int g = 0; g < G; ++g) {
        arr[g]      = dot4(xg[g], xg[g]);   // xx
        arr[10 + g] = dot4(xg[g], S4);      // xs
    }
    #pragma unroll
    for (int i = 0; i < 20; ++i) {
        float v = arr[i];
        #pragma unroll
        for (int off = 1; off < 64; off <<= 1) v += __shfl_xor(v, off);
        arr[i] = v;
    }
    float SS = 0.f;
    #pragma unroll
    for (int g = 0; g < G; ++g) SS += arr[10 + g];

    // fragment-layout byte offset for k = d0 within a 32-row tile
    const int koff = (d0 >> 5) * 1024 + ((d0 >> 4) & 1) * 512 + (d0 & 15);

    // centroid (norm folded, x16)
    const float cn = fmaxf(sqrtf(SS) * (1.0f / G), 1e-8f);
    const float cinv = FP8SCALE * (1.0f / G) / cn;
    {
        const int addr = (n >> 5) * 8192 + koff + (n & 31) * 16;
        *(int*)(cb + addr) = pk4_fp8(S4.x * cinv, S4.y * cinv, S4.z * cinv, S4.w * cinv);
    }

    // normalized x rows (x16)
    #pragma unroll
    for (int g = 0; g < G; ++g) {
        const int r = n * G + g;
        const float inv = FP8SCALE / fmaxf(sqrtf(arr[g]), 1e-8f);
        const int addr = (r >> 5) * 8192 + koff + (r & 31) * 16;
        *(int*)(xb2 + addr) = pk4_fp8(xg[g].x * inv, xg[g].y * inv, xg[g].z * inv, xg[g].w * inv);
    }

    if (lane < G) {
        const int g = lane;
        const float w = *wp, b = *bp;
        const float xx = arr[g], xs = arr[10 + g];
        const float x_norm = fmaxf(sqrtf(xx), 1e-8f);
        const float dotxe = (xs - xx) * (1.0f / (G - 1));
        const float ee = (SS - 2.f * xs + xx) * (1.0f / ((G - 1) * (G - 1)));
        const float e_norm = fmaxf(sqrtf(ee), 1e-8f);
        float cosd = fmaxf(dotxe / (x_norm * e_norm), 1e-6f);
        dlarg[n * G + g] = (fmaf(w, cosd, b) - 5.0f) * LOG2E;
    }
}

// ---------------- Kernel B: MX-fp8 K=64 MFMA GEMM + fixed-max LSE -------------
// Best measured configuration (r18, 36.8 us total): 4 waves x 32 rows x 256
// cols, 8 tiles, dbuf 2x8KB, plain syncthreads, single f32x16 acc, ROLLED
// t-loop, mfma_scale_f32_32x32x64_f8f6f4 (scales = E8M0 127 = 1.0).
// Verified-dead alternatives: pair-buffer (r19), atomic merge-fusion (r19/20),
// counted-vmcnt (r8), barrier-free 1-wave (r16), dual-acc (r7/r13 spill),
// 2-rowset (r9/r10 occupancy), 3-buffer (r11), full unroll (r14 spill).
__global__ __launch_bounds__(256, 4) void gemm_softmax_kernel(
    const unsigned char* __restrict__ xb2, const unsigned char* __restrict__ cb,
    const float* __restrict__ dlarg,
    const float* __restrict__ wp, const float* __restrict__ bp,
    float* __restrict__ pm, float* __restrict__ ps)
{
    __shared__ __align__(16) char stage[2][8192];   // 2 x 8 KB

    const int tid = threadIdx.x;
    const int wv = tid >> 6, lane = tid & 63;
    const int l31 = lane & 31, l5 = lane >> 5;

    // XCD-aware decode: rt ≡ bid (mod 8)
    const int bid = blockIdx.x;
    const int xcd = bid & 7;
    const int idx = bid >> 3;             // 0..159
    const int rt = xcd + 8 * (idx % 20);  // 0..159
    const int cs = idx / 20;              // 0..7

    const int r0 = rt * 128, c0 = cs * 256;
    const int myrow = r0 + wv * 32 + l31;
    const float w2 = (*wp) * (LOG2E / 256.0f);      // acc = 256*cos
    const float b2 = ((*bp) - 5.0f) * LOG2E;
    const float dlpre = (dlarg[myrow] - b2) / w2;   // acc value that yields dlarg
    const int labadj = myrow / G - c0 - 4 * l5;

    // resident x fragments: 4 x v8i (two coalesced 16B loads each)
    v8i xf[4];
    const unsigned char* xrow = xb2 + (size_t)(rt * 4 + wv) * 8192 + l5 * 1024 + l31 * 16;
    #pragma unroll
    for (int m = 0; m < 4; ++m) {
        const i32x4 lo = *(const i32x4*)(xrow + m * 2048);
        const i32x4 hi = *(const i32x4*)(xrow + m * 2048 + 512);
        xf[m] = __builtin_shufflevector(lo, hi, 0, 1, 2, 3, 4, 5, 6, 7);
    }

    // staging: LINEAR 8KB tile copy (fragment layout pre-baked by prep)
    #define STAGE(bufi, tt) do {                                               \
        const unsigned char* base_ = cb + (size_t)c0 * 256 + (size_t)(tt) * 8192; \
        _Pragma("unroll")                                                      \
        for (int c_ = 0; c_ < 2; ++c_) {                                       \
            const int S_ = c_ * 256 + tid;                                     \
            __builtin_amdgcn_global_load_lds(                                  \
                (const __attribute__((address_space(1))) void*)(base_ + S_ * 16), \
                (__attribute__((address_space(3))) void*)                      \
                    ((char*)&stage[bufi][0] + S_ * 16),                        \
                16, 0, 0);                                                     \
        }                                                                      \
    } while (0)

    STAGE(0, 0);

    float s0 = 0.f, s1 = 0.f, m0 = -INFINITY;
    const char* lrow0 = &stage[0][0] + l5 * 1024 + l31 * 16;
    const char* lrow1 = &stage[1][0] + l5 * 1024 + l31 * 16;

    __syncthreads();

    #pragma unroll 1     // MUST stay rolled: full unroll spills (r14, WRITE 352 MB)
    for (int t = 0; t < 8; ++t) {
        const int bsel = t & 1;
        if (t < 7) STAGE(bsel ^ 1, t + 1);

        const char* lrow = bsel ? lrow1 : lrow0;
        f32x16 acc = {0,0,0,0,0,0,0,0,0,0,0,0,0,0,0,0};
        #pragma unroll
        for (int m = 0; m < 4; ++m) {
            const i32x4 lo = *(const i32x4*)(lrow + m * 2048);
            const i32x4 hi = *(const i32x4*)(lrow + m * 2048 + 512);
            const v8i cf = __builtin_shufflevector(lo, hi, 0, 1, 2, 3, 4, 5, 6, 7);
            acc = __builtin_amdgcn_mfma_scale_f32_32x32x64_f8f6f4(
                      cf, xf[m], acc, 0, 0, 0, 0x7F7F7F7F, 0, 0x7F7F7F7F);
        }

        // epilogue in place on acc
        const int target = labadj - t * 32;   // pat == target -> label col
        if ((unsigned)target < 32u && !(target & 4)) {
            #pragma unroll
            for (int reg = 0; reg < 16; ++reg) {
                const int pat = (reg & 3) + 8 * (reg >> 2);
                if (pat == target) acc[reg] = dlpre;   // fma below yields dlarg
            }
        }
        #pragma unroll
        for (int reg = 0; reg < 16; reg += 2) {
            const float l0 = fmaf(w2, fmaxf(acc[reg],     2.56e-4f), b2);
            const float l1 = fmaf(w2, fmaxf(acc[reg + 1], 2.56e-4f), b2);
            s0 += exp2f(l0);
            s1 += exp2f(l1);
            m0 = fmaxf(m0, fmaxf(l0, l1));   // fuses to v_max3_f32
        }
        __syncthreads();
    }
    #undef STAGE

    float s = s0 + s1;
    float m = m0;
    s += __shfl_xor(s, 32);
    m = fmaxf(m, __shfl_xor(m, 32));
    if (lane < 32) {
        pm[cs * NG + myrow] = m;
        ps[cs * NG + myrow] = s;
    }
}

// ---------------- Kernel C: merge column-split partials + block partial sums ----
__global__ __launch_bounds__(256) void merge_kernel(
    const float* __restrict__ pm, const float* __restrict__ ps,
    const float* __restrict__ dlarg,
    float* __restrict__ part_loss, float* __restrict__ part_corr)
{
    const int r = blockIdx.x * 256 + threadIdx.x;
    float M = -INFINITY, S = 0.f;
    #pragma unroll
    for (int c = 0; c < 8; ++c) {
        M = fmaxf(M, pm[c * NG + r]);
        S += ps[c * NG + r];
    }
    const float dlv = dlarg[r];
    float loss = LN2 * (log2f(S) - dlv);
    float corr = (M == dlv) ? 1.0f : 0.0f;

    #pragma unroll
    for (int off = 1; off < 64; off <<= 1) {
        loss += __shfl_xor(loss, off);
        corr += __shfl_xor(corr, off);
    }
    __shared__ float rl[4], rc[4];
    const int wave = threadIdx.x >> 6, lane = threadIdx.x & 63;
    if (lane == 0) { rl[wave] = loss; rc[wave] = corr; }
    __syncthreads();
    if (threadIdx.x == 0) {
        part_loss[blockIdx.x] = rl[0] + rl[1] + rl[2] + rl[3];
        part_corr[blockIdx.x] = rc[0] + rc[1] + rc[2] + rc[3];
    }
}

// ---------------- Kernel D: final tiny reduction (80 partials) ----------------
__global__ __launch_bounds__(64) void finalize_kernel(
    const float* __restrict__ part_loss, const float* __restrict__ part_corr,
    float* __restrict__ out)
{
    const int t = threadIdx.x;
    float ls = (t < 80 ? part_loss[t] : 0.f) + (t + 64 < 80 ? part_loss[t + 64] : 0.f);
    float cs = (t < 80 ? part_corr[t] : 0.f) + (t + 64 < 80 ? part_corr[t + 64] : 0.f);
    #pragma unroll
    for (int off = 1; off < 64; off <<= 1) { ls += __shfl_xor(ls, off); cs += __shfl_xor(cs, off); }
    if (t == 0) {
        out[0] = ls / (float)NG;
        out[1] = 100.0f * cs / (float)NG;
    }
}

extern "C" void kernel_launch(void* const* d_in, const int* in_sizes, int n_in,
                              void* d_out, int out_size, void* d_ws, size_t ws_size,
                              hipStream_t stream) {
    const float* x  = (const float*)d_in[0];
    const float* wp = (const float*)d_in[1];
    const float* bp = (const float*)d_in[2];

    unsigned char* xb2 = (unsigned char*)d_ws;             // NG*D bytes   = 5.24 MB
    unsigned char* cb  = xb2 + (size_t)NG * D;             // NSPK*D bytes = 0.52 MB
    float* dlg = (float*)(cb + (size_t)NSPK * D);          // NG floats
    float* pm  = dlg + NG;                                 // 8*NG
    float* ps  = pm + 8 * NG;                              // 8*NG
    float* pl  = ps + 8 * NG;                              // 80
    float* pc  = pl + 128;                                 // 80

    prep_kernel<<<NSPK / 4, 256, 0, stream>>>(x, wp, bp, xb2, cb, dlg);
    gemm_softmax_kernel<<<1280, 256, 0, stream>>>(xb2, cb, dlg, wp, bp, pm, ps);
    merge_kernel<<<NG / 256, 256, 0, stream>>>(pm, ps, dlg, pl, pc);
    finalize_kernel<<<1, 64, 0, stream>>>(pl, pc, (float*)d_out);
}